// Round 1
// baseline (2367.932 us; speedup 1.0000x reference)
//
#include <hip/hip_runtime.h>
#include <math.h>

#define NPn 100000
#define NAn 50000
#define NTn 150000
#define En  200000

// ---------------- CSR build ----------------

__global__ __launch_bounds__(256) void hist_k(const int* __restrict__ dst, int E, int* __restrict__ deg) {
  int i = blockIdx.x * 256 + threadIdx.x;
  if (i < E) atomicAdd(&deg[dst[i]], 1);
}

// single-block chunked exclusive scan: rowptr[0..n], rowptr[n]=total
__global__ __launch_bounds__(1024) void scan_k(const int* __restrict__ deg, int n, int* __restrict__ rowptr) {
  __shared__ int sums[1024];
  int t = threadIdx.x;
  int chunk = (n + 1023) >> 10;
  int lo = t * chunk; if (lo > n) lo = n;
  int hi = lo + chunk; if (hi > n) hi = n;
  int s = 0;
  for (int i = lo; i < hi; ++i) s += deg[i];
  sums[t] = s;
  __syncthreads();
  for (int off = 1; off < 1024; off <<= 1) {
    int v = (t >= off) ? sums[t - off] : 0;
    __syncthreads();
    sums[t] += v;
    __syncthreads();
  }
  int run = (t == 0) ? 0 : sums[t - 1];
  for (int i = lo; i < hi; ++i) { rowptr[i] = run; run += deg[i]; }
  if (t == 1023) rowptr[n] = run;
}

__global__ __launch_bounds__(256) void fill_k(const int* __restrict__ src, const int* __restrict__ dst, int E,
                                              int* cursor, int* __restrict__ colsrc) {
  int i = blockIdx.x * 256 + threadIdx.x;
  if (i < E) {
    int p = atomicAdd(&cursor[dst[i]], 1);
    colsrc[p] = src[i];
  }
}

// ---------------- fused relation weights ----------------
// Wf[b] = W[L][s_t] @ blockdiag(R[L][et]),  bf[b] = b[L][s_t] @ blockdiag(R)
// b = L*6 + et*2 + which (which: 0 = K/a_rel, 1 = V/m_rel)
__global__ __launch_bounds__(256) void fuse_k(const float* __restrict__ kW, const float* __restrict__ kb,
                                              const float* __restrict__ vW, const float* __restrict__ vb,
                                              const float* __restrict__ a_rel, const float* __restrict__ m_rel,
                                              float* __restrict__ Wf, float* __restrict__ bfv) {
  int b = blockIdx.x;
  int L = b / 6, et = (b % 6) / 2, which = b & 1;
  int s_t = (et == 1) ? 1 : 0;
  const float* W = which ? vW : kW;
  const float* bb = which ? vb : kb;
  const float* R = which ? m_rel : a_rel;
  const float* Wsrc = W + (size_t)(L * 2 + s_t) * 128 * 128;
  const float* bsrc = bb + (size_t)(L * 2 + s_t) * 128;
  const float* Rsrc = R + (size_t)(L * 3 + et) * 4 * 32 * 32;
  float* Wdst = Wf + (size_t)b * 128 * 128;
  float* bdst = bfv + (size_t)b * 128;
  for (int idx = threadIdx.x; idx < 128 * 128; idx += 256) {
    int i = idx >> 7, c = idx & 127;
    int h = c >> 5, cc = c & 31;
    const float* r = Rsrc + (size_t)h * 32 * 32 + cc;   // R[h][d][cc], stride 32
    const float* w = Wsrc + (size_t)i * 128 + h * 32;
    float s = 0.f;
    #pragma unroll 8
    for (int d = 0; d < 32; ++d) s += w[d] * r[d * 32];
    Wdst[idx] = s;
  }
  for (int c = threadIdx.x; c < 128; c += 256) {
    int h = c >> 5, cc = c & 31;
    float s = 0.f;
    for (int d = 0; d < 32; ++d) s += bsrc[h * 32 + d] * Rsrc[((size_t)h * 32 + d) * 32 + cc];
    bdst[c] = s;
  }
}

// ---------------- GEMM: Y[N,128] = act(X[N,128]) @ W[128,128] + B ----------------
// MODE 0: Y = X@W + B
// MODE 1: Y = g*(gelu(X)@W + B) + (1-g)*skipx   (in place: Y may alias skipx)
template <int MODE>
__global__ __launch_bounds__(256) void gemm128(const float* __restrict__ X, const float* __restrict__ W,
                                               const float* __restrict__ B, float* Y, int N,
                                               const float* skipp, const float* skipx) {
  __shared__ float xt[64][132];
  int t = threadIdx.x;
  int tr = t >> 4, tc = t & 15;          // 16x16 thread grid: 4 rows x 8 cols each
  float4 b0 = *reinterpret_cast<const float4*>(B + tc * 8);
  float4 b1 = *reinterpret_cast<const float4*>(B + tc * 8 + 4);
  float bb[8] = {b0.x, b0.y, b0.z, b0.w, b1.x, b1.y, b1.z, b1.w};
  float g = 0.f;
  if (MODE == 1) g = 1.f / (1.f + expf(-*skipp));

  for (int rbase = blockIdx.x * 64; rbase < N; rbase += gridDim.x * 64) {
    int rows = N - rbase; if (rows > 64) rows = 64;
    for (int i = t; i < rows * 32; i += 256) {
      int r = i >> 5, c4 = i & 31;
      float4 v = reinterpret_cast<const float4*>(X + (size_t)(rbase + r) * 128)[c4];
      if (MODE == 1) {
        v.x = 0.5f * v.x * (1.f + erff(v.x * 0.70710678118654752f));
        v.y = 0.5f * v.y * (1.f + erff(v.y * 0.70710678118654752f));
        v.z = 0.5f * v.z * (1.f + erff(v.z * 0.70710678118654752f));
        v.w = 0.5f * v.w * (1.f + erff(v.w * 0.70710678118654752f));
      }
      *reinterpret_cast<float4*>(&xt[r][c4 * 4]) = v;
    }
    __syncthreads();

    float acc_[4][8];
    #pragma unroll
    for (int i = 0; i < 4; ++i)
      #pragma unroll
      for (int j = 0; j < 8; ++j) acc_[i][j] = 0.f;

    #pragma unroll 4
    for (int k = 0; k < 128; ++k) {
      float4 w0 = *reinterpret_cast<const float4*>(W + (size_t)k * 128 + tc * 8);
      float4 w1 = *reinterpret_cast<const float4*>(W + (size_t)k * 128 + tc * 8 + 4);
      float wv[8] = {w0.x, w0.y, w0.z, w0.w, w1.x, w1.y, w1.z, w1.w};
      #pragma unroll
      for (int i = 0; i < 4; ++i) {
        float xv = xt[tr * 4 + i][k];
        #pragma unroll
        for (int j = 0; j < 8; ++j) acc_[i][j] = fmaf(xv, wv[j], acc_[i][j]);
      }
    }
    __syncthreads();

    #pragma unroll
    for (int i = 0; i < 4; ++i) {
      int r = rbase + tr * 4 + i;
      if (r < N) {
        float y[8];
        #pragma unroll
        for (int j = 0; j < 8; ++j) y[j] = acc_[i][j] + bb[j];
        if (MODE == 1) {
          const float* sp = skipx + (size_t)r * 128 + tc * 8;
          float4 s0 = *reinterpret_cast<const float4*>(sp);
          float4 s1 = *reinterpret_cast<const float4*>(sp + 4);
          float sv[8] = {s0.x, s0.y, s0.z, s0.w, s1.x, s1.y, s1.z, s1.w};
          #pragma unroll
          for (int j = 0; j < 8; ++j) y[j] = g * y[j] + (1.f - g) * sv[j];
        }
        float4 o0 = {y[0], y[1], y[2], y[3]};
        float4 o1 = {y[4], y[5], y[6], y[7]};
        float* yp = Y + (size_t)r * 128 + tc * 8;
        *reinterpret_cast<float4*>(yp) = o0;
        *reinterpret_cast<float4*>(yp + 4) = o1;
      }
    }
  }
}

// ---------------- edge attention: one wave per dst node ----------------
__global__ __launch_bounds__(256) void edge_attn(const int* __restrict__ rowptr, const int* __restrict__ colsrc,
                                                 const float* __restrict__ kt, const float* __restrict__ vt,
                                                 const float* __restrict__ q, float* acc,
                                                 const float* __restrict__ prel, int n_dst) {
  int node = (blockIdx.x * 256 + threadIdx.x) >> 6;
  if (node >= n_dst) return;
  int lane = threadIdx.x & 63;
  int h = lane >> 4;
  int rs = rowptr[node], re = rowptr[node + 1];
  if (rs >= re) return;
  float2 qv = *reinterpret_cast<const float2*>(q + (size_t)node * 128 + lane * 2);
  float pr = prel[h] * 0.17677669529663687f;  // p_rel * 1/sqrt(32)
  float m = -3.0e38f;
  for (int i = rs; i < re; ++i) {
    int s = colsrc[i];
    float2 kv = *reinterpret_cast<const float2*>(kt + (size_t)s * 128 + lane * 2);
    float p = qv.x * kv.x + qv.y * kv.y;
    p += __shfl_xor(p, 1); p += __shfl_xor(p, 2); p += __shfl_xor(p, 4); p += __shfl_xor(p, 8);
    m = fmaxf(m, p * pr);
  }
  float den = 0.f, n0 = 0.f, n1 = 0.f;
  for (int i = rs; i < re; ++i) {
    int s = colsrc[i];
    float2 kv = *reinterpret_cast<const float2*>(kt + (size_t)s * 128 + lane * 2);
    float p = qv.x * kv.x + qv.y * kv.y;
    p += __shfl_xor(p, 1); p += __shfl_xor(p, 2); p += __shfl_xor(p, 4); p += __shfl_xor(p, 8);
    float w = expf(p * pr - m);
    den += w;
    float2 vv = *reinterpret_cast<const float2*>(vt + (size_t)s * 128 + lane * 2);
    n0 += w * vv.x; n1 += w * vv.y;
  }
  float inv = 1.f / den;
  float* ap = acc + (size_t)node * 128 + lane * 2;
  ap[0] += n0 * inv;
  ap[1] += n1 * inv;
}

// ---------------- host ----------------

extern "C" void kernel_launch(void* const* d_in, const int* in_sizes, int n_in,
                              void* d_out, int out_size, void* d_ws, size_t ws_size,
                              hipStream_t stream) {
  const float* x_paper  = (const float*)d_in[0];
  const float* x_author = (const float*)d_in[1];
  const int* e[3] = {(const int*)d_in[2], (const int*)d_in[3], (const int*)d_in[4]};
  const float* linW = (const float*)d_in[5];
  const float* linb = (const float*)d_in[6];
  const float* kW = (const float*)d_in[7];
  const float* kb = (const float*)d_in[8];
  const float* qW = (const float*)d_in[9];
  const float* qb = (const float*)d_in[10];
  const float* vW = (const float*)d_in[11];
  const float* vb = (const float*)d_in[12];
  const float* aW = (const float*)d_in[13];
  const float* ab = (const float*)d_in[14];
  const float* skipv = (const float*)d_in[15];
  const float* a_rel = (const float*)d_in[16];
  const float* m_rel = (const float*)d_in[17];
  const float* prel  = (const float*)d_in[18];

  char* ws = (char*)d_ws;
  size_t off = 0;
  auto alloc = [&](size_t b) { char* p = ws + off; off = (off + b + 255) & ~(size_t)255; return p; };
  float* q   = (float*)alloc((size_t)NTn * 128 * 4);
  float* kt  = (float*)alloc((size_t)NPn * 128 * 4);
  float* vt  = (float*)alloc((size_t)NPn * 128 * 4);
  float* acc = (float*)alloc((size_t)NTn * 128 * 4);
  int* rowptr[3];
  rowptr[0] = (int*)alloc((NPn + 1) * 4);
  rowptr[1] = (int*)alloc((NPn + 1) * 4);
  rowptr[2] = (int*)alloc((NAn + 1) * 4);
  int* colsrc[3];
  colsrc[0] = (int*)alloc((size_t)En * 4);
  colsrc[1] = (int*)alloc((size_t)En * 4);
  colsrc[2] = (int*)alloc((size_t)En * 4);
  int* itmp = (int*)alloc((NPn + 1) * 4);
  float* Wf = (float*)alloc((size_t)12 * 128 * 128 * 4);
  float* bfv = (float*)alloc((size_t)12 * 128 * 4);

  const int ndst[3] = {NPn, NPn, NAn};
  const int stype[3] = {0, 1, 0};
  const int dtype[3] = {0, 0, 1};

  // CSR per edge type (edges constant across layers)
  for (int et = 0; et < 3; ++et) {
    int n = ndst[et];
    hipMemsetAsync(itmp, 0, (size_t)n * 4, stream);
    hist_k<<<(En + 255) / 256, 256, 0, stream>>>(e[et] + En, En, itmp);
    scan_k<<<1, 1024, 0, stream>>>(itmp, n, rowptr[et]);
    hipMemcpyAsync(itmp, rowptr[et], (size_t)n * 4, hipMemcpyDeviceToDevice, stream);
    fill_k<<<(En + 255) / 256, 256, 0, stream>>>(e[et], e[et] + En, En, itmp, colsrc[et]);
  }

  fuse_k<<<12, 256, 0, stream>>>(kW, kb, vW, vb, a_rel, m_rel, Wf, bfv);

  float* xs = (float*)d_out;  // features live in d_out, updated in place
  gemm128<0><<<(NPn + 63) / 64, 256, 0, stream>>>(x_paper, linW, linb, xs, NPn, nullptr, nullptr);
  gemm128<0><<<(NAn + 63) / 64, 256, 0, stream>>>(x_author, linW + 16384, linb + 128,
                                                  xs + (size_t)NPn * 128, NAn, nullptr, nullptr);

  for (int L = 0; L < 2; ++L) {
    gemm128<0><<<(NPn + 63) / 64, 256, 0, stream>>>(xs, qW + (size_t)(L * 2) * 16384, qb + (L * 2) * 128,
                                                    q, NPn, nullptr, nullptr);
    gemm128<0><<<(NAn + 63) / 64, 256, 0, stream>>>(xs + (size_t)NPn * 128, qW + (size_t)(L * 2 + 1) * 16384,
                                                    qb + (L * 2 + 1) * 128, q + (size_t)NPn * 128, NAn,
                                                    nullptr, nullptr);
    hipMemsetAsync(acc, 0, (size_t)NTn * 128 * 4, stream);
    for (int et = 0; et < 3; ++et) {
      int st = stype[et], dt = dtype[et];
      const float* sx = st ? xs + (size_t)NPn * 128 : xs;
      int nsrc = st ? NAn : NPn;
      int b = L * 6 + et * 2;
      gemm128<0><<<(nsrc + 63) / 64, 256, 0, stream>>>(sx, Wf + (size_t)b * 16384, bfv + (size_t)b * 128,
                                                       kt, nsrc, nullptr, nullptr);
      gemm128<0><<<(nsrc + 63) / 64, 256, 0, stream>>>(sx, Wf + (size_t)(b + 1) * 16384, bfv + (size_t)(b + 1) * 128,
                                                       vt, nsrc, nullptr, nullptr);
      int nd = ndst[et];
      const float* qp = dt ? q + (size_t)NPn * 128 : q;
      float* ap = dt ? acc + (size_t)NPn * 128 : acc;
      edge_attn<<<(nd + 3) / 4, 256, 0, stream>>>(rowptr[et], colsrc[et], kt, vt, qp, ap,
                                                  prel + (size_t)(L * 3 + et) * 4, nd);
    }
    gemm128<1><<<(NPn + 63) / 64, 256, 0, stream>>>(acc, aW + (size_t)(L * 2) * 16384, ab + (L * 2) * 128,
                                                    xs, NPn, skipv + L * 2, xs);
    gemm128<1><<<(NAn + 63) / 64, 256, 0, stream>>>(acc + (size_t)NPn * 128, aW + (size_t)(L * 2 + 1) * 16384,
                                                    ab + (L * 2 + 1) * 128, xs + (size_t)NPn * 128, NAn,
                                                    skipv + L * 2 + 1, xs + (size_t)NPn * 128);
  }
}

// Round 5
// 973.951 us; speedup vs baseline: 2.4313x; 2.4313x over previous
//
#include <hip/hip_runtime.h>
#include <math.h>

#define NPn 100000
#define NAn 50000
#define NTn 150000
#define En  200000
#define SCAN_N 250000

typedef short s16x8 __attribute__((ext_vector_type(8)));
typedef float f32x4 __attribute__((ext_vector_type(4)));

__device__ __forceinline__ unsigned short f2bfbits(float f) {
  unsigned u = __builtin_bit_cast(unsigned, f);
  return (unsigned short)((u + 0x7fffu + ((u >> 16) & 1u)) >> 16);
}
__device__ __forceinline__ float bf2f(unsigned short b) {
  return __builtin_bit_cast(float, (unsigned)b << 16);
}

// ---------------- CSR build (combined over 3 edge types) ----------------
// deg/cursor/S index space: et0 papers [0,100000), et1 papers [100000,200000),
// et2 authors [200000,250000).

__global__ __launch_bounds__(256) void hist3_k(const int* __restrict__ e0, const int* __restrict__ e1,
                                               const int* __restrict__ e2, int* __restrict__ deg) {
  int i = blockIdx.x * 256 + threadIdx.x;
  int et = blockIdx.y;
  if (i >= En) return;
  const int* d = et == 0 ? e0 : (et == 1 ? e1 : e2);
  int etoff = et == 0 ? 0 : (et == 1 ? 100000 : 200000);
  atomicAdd(&deg[etoff + d[En + i]], 1);
}

__global__ __launch_bounds__(256) void scan1_k(const int* __restrict__ deg, int* __restrict__ bsum) {
  int t = threadIdx.x, lane = t & 63, wv = t >> 6;
  int base = blockIdx.x * 1024 + t * 4;
  int a0 = 0, a1 = 0, a2 = 0, a3 = 0;
  if (base + 3 < SCAN_N) {
    int4 v = *reinterpret_cast<const int4*>(deg + base);
    a0 = v.x; a1 = v.y; a2 = v.z; a3 = v.w;
  } else {
    if (base + 0 < SCAN_N) a0 = deg[base + 0];
    if (base + 1 < SCAN_N) a1 = deg[base + 1];
    if (base + 2 < SCAN_N) a2 = deg[base + 2];
    if (base + 3 < SCAN_N) a3 = deg[base + 3];
  }
  int s = a0 + a1 + a2 + a3;
  #pragma unroll
  for (int d = 1; d < 64; d <<= 1) s += __shfl_xor(s, d);
  __shared__ int wt[4];
  if (lane == 0) wt[wv] = s;
  __syncthreads();
  if (t == 0) bsum[blockIdx.x] = wt[0] + wt[1] + wt[2] + wt[3];
}

__global__ __launch_bounds__(256) void scan2_k(int* __restrict__ bsum, int nb) {
  int t = threadIdx.x, lane = t & 63, wv = t >> 6;
  int v = (t < nb) ? bsum[t] : 0;
  int x = v;
  #pragma unroll
  for (int d = 1; d < 64; d <<= 1) {
    int y = __shfl_up(x, d);
    if (lane >= d) x += y;
  }
  __shared__ int wt[4];
  if (lane == 63) wt[wv] = x;
  __syncthreads();
  int off = 0;
  for (int w = 0; w < wv; ++w) off += wt[w];
  if (t < nb) bsum[t] = x + off - v;  // exclusive
}

__global__ __launch_bounds__(256) void scan3_k(const int* __restrict__ deg, const int* __restrict__ bpre,
                                               int* __restrict__ S) {
  int t = threadIdx.x, lane = t & 63, wv = t >> 6;
  int base = blockIdx.x * 1024 + t * 4;
  int a[4] = {0, 0, 0, 0};
  if (base + 3 < SCAN_N) {
    int4 v = *reinterpret_cast<const int4*>(deg + base);
    a[0] = v.x; a[1] = v.y; a[2] = v.z; a[3] = v.w;
  } else {
    #pragma unroll
    for (int j = 0; j < 4; ++j) if (base + j < SCAN_N) a[j] = deg[base + j];
  }
  int s = a[0] + a[1] + a[2] + a[3];
  int x = s;
  #pragma unroll
  for (int d = 1; d < 64; d <<= 1) {
    int y = __shfl_up(x, d);
    if (lane >= d) x += y;
  }
  __shared__ int wt[4];
  if (lane == 63) wt[wv] = x;
  __syncthreads();
  int off = bpre[blockIdx.x];
  for (int w = 0; w < wv; ++w) off += wt[w];
  int ex = off + x - s;
  #pragma unroll
  for (int j = 0; j < 4; ++j) {
    int idx = base + j;
    if (idx < SCAN_N) {
      S[idx] = ex;
      ex += a[j];
      if (idx == SCAN_N - 1) S[SCAN_N] = ex;
    }
  }
}

__global__ __launch_bounds__(256) void fill3_k(const int* __restrict__ e0, const int* __restrict__ e1,
                                               const int* __restrict__ e2, int* cur, int* __restrict__ col) {
  int i = blockIdx.x * 256 + threadIdx.x;
  int et = blockIdx.y;
  if (i >= En) return;
  const int* ep = et == 0 ? e0 : (et == 1 ? e1 : e2);
  int etoff = et == 0 ? 0 : (et == 1 ? 100000 : 200000);
  int p = atomicAdd(&cur[etoff + ep[En + i]], 1);
  col[p] = ep[i];
}

// ---------------- fused relation weights (fp32) ----------------
__global__ __launch_bounds__(256) void fuse_k(const float* __restrict__ kW, const float* __restrict__ kb,
                                              const float* __restrict__ vW, const float* __restrict__ vb,
                                              const float* __restrict__ a_rel, const float* __restrict__ m_rel,
                                              float* __restrict__ Wf, float* __restrict__ bfv) {
  int b = blockIdx.x;
  int L = b / 6, et = (b % 6) / 2, which = b & 1;
  int s_t = (et == 1) ? 1 : 0;
  const float* W = which ? vW : kW;
  const float* bb = which ? vb : kb;
  const float* R = which ? m_rel : a_rel;
  const float* Wsrc = W + (size_t)(L * 2 + s_t) * 128 * 128;
  const float* bsrc = bb + (size_t)(L * 2 + s_t) * 128;
  const float* Rsrc = R + (size_t)(L * 3 + et) * 4 * 32 * 32;
  float* Wdst = Wf + (size_t)b * 128 * 128;
  float* bdst = bfv + (size_t)b * 128;
  for (int idx = threadIdx.x; idx < 128 * 128; idx += 256) {
    int i = idx >> 7, c = idx & 127;
    int h = c >> 5, cc = c & 31;
    const float* r = Rsrc + (size_t)h * 32 * 32 + cc;
    const float* w = Wsrc + (size_t)i * 128 + h * 32;
    float s = 0.f;
    #pragma unroll 8
    for (int d = 0; d < 32; ++d) s += w[d] * r[d * 32];
    Wdst[idx] = s;
  }
  for (int c = threadIdx.x; c < 128; c += 256) {
    int h = c >> 5, cc = c & 31;
    float s = 0.f;
    for (int d = 0; d < 32; ++d) s += bsrc[h * 32 + d] * Rsrc[((size_t)h * 32 + d) * 32 + cc];
    bdst[c] = s;
  }
}

// ---------------- pack weights to bf16 B-fragment order ----------------
// Wp[m][ks][ct][lane][i] = bf16(W[k][n]), k=ks*32+(lane>>4)*8+i, n=ct*16+(lane&15)
__global__ __launch_bounds__(256) void pack_k(const float* __restrict__ linW, const float* __restrict__ qW,
                                              const float* __restrict__ aW, const float* __restrict__ Wf,
                                              unsigned short* __restrict__ Wp) {
  int m = blockIdx.x;
  const float* src;
  if (m < 2) src = linW + (size_t)m * 16384;
  else if (m < 6) src = qW + (size_t)(m - 2) * 16384;
  else if (m < 18) src = Wf + (size_t)(m - 6) * 16384;
  else src = aW + (size_t)(m - 18) * 16384;
  int lane = threadIdx.x & 63, wv = threadIdx.x >> 6;
  unsigned short* dst = Wp + (size_t)m * 16384;
  for (int ct = 0; ct < 8; ++ct) {
    s16x8 t;
    #pragma unroll
    for (int i = 0; i < 8; ++i) {
      int k = wv * 32 + (lane >> 4) * 8 + i;
      int n = ct * 16 + (lane & 15);
      t[i] = (short)f2bfbits(src[k * 128 + n]);
    }
    *reinterpret_cast<s16x8*>(dst + ((size_t)(wv * 8 + ct) * 64 + lane) * 8) = t;
  }
}

// ---------------- fp32 -> bf16 converts ----------------
__global__ __launch_bounds__(256) void cvt_k(const float* __restrict__ src, unsigned short* __restrict__ dst, int n4) {
  int i = blockIdx.x * 256 + threadIdx.x;
  if (i >= n4) return;
  float4 v = reinterpret_cast<const float4*>(src)[i];
  ushort4 o;
  o.x = f2bfbits(v.x); o.y = f2bfbits(v.y); o.z = f2bfbits(v.z); o.w = f2bfbits(v.w);
  reinterpret_cast<ushort4*>(dst)[i] = o;
}

__global__ __launch_bounds__(256) void gelu_cvt_k(const float* __restrict__ src, unsigned short* __restrict__ dst, int n4) {
  int i = blockIdx.x * 256 + threadIdx.x;
  if (i >= n4) return;
  float4 v = reinterpret_cast<const float4*>(src)[i];
  v.x = 0.5f * v.x * (1.f + erff(v.x * 0.70710678118654752f));
  v.y = 0.5f * v.y * (1.f + erff(v.y * 0.70710678118654752f));
  v.z = 0.5f * v.z * (1.f + erff(v.z * 0.70710678118654752f));
  v.w = 0.5f * v.w * (1.f + erff(v.w * 0.70710678118654752f));
  ushort4 o;
  o.x = f2bfbits(v.x); o.y = f2bfbits(v.y); o.z = f2bfbits(v.z); o.w = f2bfbits(v.w);
  reinterpret_cast<ushort4*>(dst)[i] = o;
}

// ---------------- MFMA GEMM: Y[N,128] = Xb[N,128] @ W + bias ----------------
// MODE 0: fp32 out. MODE 1: fp32 out + bf16 shadow. MODE 2: skip-blend, fp32 + bf16 shadow.
// MODE 3: bf16 out only.
struct GJob {
  const unsigned short* X;
  const unsigned short* W;
  const float* bias;
  float* Yf;
  unsigned short* Yb;
  const float* skipx;
  const float* skipp;
  int N;
};

template <int MODE>
__global__ __launch_bounds__(256, 2) void gemm_k(GJob ja, GJob jb) {
  GJob j = blockIdx.y ? jb : ja;
  int ntj = (j.N + 63) >> 6;
  if ((int)blockIdx.x >= ntj) return;
  int lane = threadIdx.x & 63, wv = threadIdx.x >> 6;

  // B fragments in registers: 4 k-steps x 8 col-tiles
  s16x8 bfr[4][8];
  #pragma unroll
  for (int ks = 0; ks < 4; ++ks)
    #pragma unroll
    for (int ct = 0; ct < 8; ++ct)
      bfr[ks][ct] = *reinterpret_cast<const s16x8*>(j.W + ((size_t)(ks * 8 + ct) * 64 + lane) * 8);

  float bias_[8];
  #pragma unroll
  for (int ct = 0; ct < 8; ++ct) bias_[ct] = j.bias[ct * 16 + (lane & 15)];
  float g = 0.f;
  if (MODE == 2) g = 1.f / (1.f + __expf(-*j.skipp));

  for (int tile = blockIdx.x; tile < ntj; tile += gridDim.x) {
    int rbase = tile * 64 + wv * 16;
    int arow = rbase + (lane & 15);
    if (arow >= j.N) arow = j.N - 1;
    const unsigned short* xp = j.X + (size_t)arow * 128 + (lane >> 4) * 8;
    s16x8 af[4];
    #pragma unroll
    for (int ks = 0; ks < 4; ++ks) af[ks] = *reinterpret_cast<const s16x8*>(xp + ks * 32);

    f32x4 acc[8];
    #pragma unroll
    for (int ct = 0; ct < 8; ++ct) acc[ct] = (f32x4){0.f, 0.f, 0.f, 0.f};
    #pragma unroll
    for (int ks = 0; ks < 4; ++ks)
      #pragma unroll
      for (int ct = 0; ct < 8; ++ct)
        acc[ct] = __builtin_amdgcn_mfma_f32_16x16x32_bf16(af[ks], bfr[ks][ct], acc[ct], 0, 0, 0);

    int c = lane & 15;
    int r0 = rbase + (lane >> 4) * 4;
    #pragma unroll
    for (int ct = 0; ct < 8; ++ct) {
      #pragma unroll
      for (int i = 0; i < 4; ++i) {
        int r = r0 + i;
        if (r < j.N) {
          float y = acc[ct][i] + bias_[ct];
          size_t off = (size_t)r * 128 + ct * 16 + c;
          if (MODE == 2) y = g * y + (1.f - g) * j.skipx[off];
          if (MODE != 3) j.Yf[off] = y;
          if (MODE != 0) j.Yb[off] = f2bfbits(y);
        }
      }
    }
  }
}

// ---------------- edge attention: one wave per dst node, online softmax ----------------
__global__ __launch_bounds__(256) void edge_attn(const int* __restrict__ S, int etoff,
                                                 const int* __restrict__ col,
                                                 const unsigned short* __restrict__ ktb,
                                                 const unsigned short* __restrict__ vtb,
                                                 const float* __restrict__ q, float* acc,
                                                 const float* __restrict__ prel, int n_dst) {
  int node = (blockIdx.x * 256 + threadIdx.x) >> 6;
  if (node >= n_dst) return;
  int lane = threadIdx.x & 63;
  int h = lane >> 4;
  int rs = S[etoff + node], re = S[etoff + node + 1];
  if (rs >= re) return;
  float2 qv = *reinterpret_cast<const float2*>(q + (size_t)node * 128 + lane * 2);
  float pr = prel[h] * 0.17677669529663687f;
  float m = -3.0e38f, den = 0.f, n0 = 0.f, n1 = 0.f;
  for (int i = rs; i < re; ++i) {
    int s = col[i];
    ushort2 kv = *reinterpret_cast<const ushort2*>(ktb + (size_t)s * 128 + lane * 2);
    float p = qv.x * bf2f(kv.x) + qv.y * bf2f(kv.y);
    p += __shfl_xor(p, 1); p += __shfl_xor(p, 2); p += __shfl_xor(p, 4); p += __shfl_xor(p, 8);
    float pm = p * pr;
    ushort2 vv = *reinterpret_cast<const ushort2*>(vtb + (size_t)s * 128 + lane * 2);
    float nm = fmaxf(m, pm);
    float sc = __expf(m - nm);
    float w = __expf(pm - nm);
    den = den * sc + w;
    n0 = n0 * sc + w * bf2f(vv.x);
    n1 = n1 * sc + w * bf2f(vv.y);
    m = nm;
  }
  float inv = 1.f / den;
  float* ap = acc + (size_t)node * 128 + lane * 2;
  ap[0] += n0 * inv;
  ap[1] += n1 * inv;
}

// ---------------- host ----------------
extern "C" void kernel_launch(void* const* d_in, const int* in_sizes, int n_in,
                              void* d_out, int out_size, void* d_ws, size_t ws_size,
                              hipStream_t stream) {
  const float* x_paper  = (const float*)d_in[0];
  const float* x_author = (const float*)d_in[1];
  const int* e[3] = {(const int*)d_in[2], (const int*)d_in[3], (const int*)d_in[4]};
  const float* linW = (const float*)d_in[5];
  const float* linb = (const float*)d_in[6];
  const float* kW = (const float*)d_in[7];
  const float* kb = (const float*)d_in[8];
  const float* qW = (const float*)d_in[9];
  const float* qb = (const float*)d_in[10];
  const float* vW = (const float*)d_in[11];
  const float* vb = (const float*)d_in[12];
  const float* aW = (const float*)d_in[13];
  const float* ab = (const float*)d_in[14];
  const float* skipv = (const float*)d_in[15];
  const float* a_rel = (const float*)d_in[16];
  const float* m_rel = (const float*)d_in[17];
  const float* prel  = (const float*)d_in[18];

  char* ws = (char*)d_ws;
  size_t off = 0;
  auto alloc = [&](size_t b) { char* p = ws + off; off = (off + b + 255) & ~(size_t)255; return p; };
  float* q             = (float*)alloc((size_t)NTn * 128 * 4);
  float* acc           = (float*)alloc((size_t)NTn * 128 * 4);
  unsigned short* ktb  = (unsigned short*)alloc((size_t)NPn * 128 * 2);
  unsigned short* vtb  = (unsigned short*)alloc((size_t)NPn * 128 * 2);
  unsigned short* gb   = ktb;  // alias: gb (150k*128*2 = 38.4MB) overlays ktb+vtb (51.2MB), dead by then
  unsigned short* xb   = (unsigned short*)alloc((size_t)NTn * 128 * 2);
  int* deg   = (int*)alloc((size_t)SCAN_N * 4);
  int* cur   = (int*)alloc((size_t)SCAN_N * 4);
  int* S     = (int*)alloc((size_t)(SCAN_N + 1) * 4);
  int* bsum  = (int*)alloc(256 * 4);
  int* col   = (int*)alloc((size_t)3 * En * 4);
  float* Wf  = (float*)alloc((size_t)12 * 16384 * 4);
  float* bfv = (float*)alloc((size_t)12 * 128 * 4);
  unsigned short* Wp = (unsigned short*)alloc((size_t)22 * 16384 * 2);

  // ---- CSR (combined) ----
  hipMemsetAsync(deg, 0, (size_t)SCAN_N * 4, stream);
  hist3_k<<<dim3(782, 3), 256, 0, stream>>>(e[0], e[1], e[2], deg);
  scan1_k<<<245, 256, 0, stream>>>(deg, bsum);
  scan2_k<<<1, 256, 0, stream>>>(bsum, 245);
  scan3_k<<<245, 256, 0, stream>>>(deg, bsum, S);
  hipMemcpyAsync(cur, S, (size_t)SCAN_N * 4, hipMemcpyDeviceToDevice, stream);
  fill3_k<<<dim3(782, 3), 256, 0, stream>>>(e[0], e[1], e[2], cur, col);

  // ---- weights ----
  fuse_k<<<12, 256, 0, stream>>>(kW, kb, vW, vb, a_rel, m_rel, Wf, bfv);
  pack_k<<<22, 256, 0, stream>>>(linW, qW, aW, Wf, Wp);

  // ---- input convert ----
  cvt_k<<<12500, 256, 0, stream>>>(x_paper, xb, NPn * 128 / 4);
  cvt_k<<<6250, 256, 0, stream>>>(x_author, xb + (size_t)NPn * 128, NAn * 128 / 4);

  float* xs = (float*)d_out;
  const dim3 gg(782, 2);

  // ---- input projection (fp32 out + bf16 shadow, xb in-place) ----
  {
    GJob jp = {xb, Wp + 0 * 16384, linb, xs, xb, nullptr, nullptr, NPn};
    GJob jat = {xb + (size_t)NPn * 128, Wp + 1 * 16384, linb + 128,
                xs + (size_t)NPn * 128, xb + (size_t)NPn * 128, nullptr, nullptr, NAn};
    gemm_k<1><<<gg, 256, 0, stream>>>(jp, jat);
  }

  const int etoffs[3] = {0, 100000, 200000};
  const int stype[3] = {0, 1, 0};
  const int dtype[3] = {0, 0, 1};
  const int ndst[3] = {NPn, NPn, NAn};

  for (int L = 0; L < 2; ++L) {
    // Q projections
    {
      GJob jp = {xb, Wp + (size_t)(2 + L * 2) * 16384, qb + (L * 2) * 128, q, nullptr, nullptr, nullptr, NPn};
      GJob jat = {xb + (size_t)NPn * 128, Wp + (size_t)(3 + L * 2) * 16384, qb + (L * 2 + 1) * 128,
                  q + (size_t)NPn * 128, nullptr, nullptr, nullptr, NAn};
      gemm_k<0><<<gg, 256, 0, stream>>>(jp, jat);
    }
    hipMemsetAsync(acc, 0, (size_t)NTn * 128 * 4, stream);
    for (int et = 0; et < 3; ++et) {
      int st = stype[et], dt = dtype[et];
      const unsigned short* sx = st ? xb + (size_t)NPn * 128 : xb;
      int nsrc = st ? NAn : NPn;
      int b = L * 6 + et * 2;
      GJob jk = {sx, Wp + (size_t)(6 + b) * 16384, bfv + (size_t)b * 128, nullptr, ktb, nullptr, nullptr, nsrc};
      GJob jv = {sx, Wp + (size_t)(7 + b) * 16384, bfv + (size_t)(b + 1) * 128, nullptr, vtb, nullptr, nullptr, nsrc};
      gemm_k<3><<<gg, 256, 0, stream>>>(jk, jv);
      int nd = ndst[et];
      const float* qp = dt ? q + (size_t)NPn * 128 : q;
      float* ap = dt ? acc + (size_t)NPn * 128 : acc;
      edge_attn<<<(nd + 3) / 4, 256, 0, stream>>>(S, etoffs[et], col, ktb, vtb, qp, ap,
                                                  prel + (size_t)(L * 3 + et) * 4, nd);
    }
    // gelu(acc) -> bf16 gb
    gelu_cvt_k<<<18750, 256, 0, stream>>>(acc, gb, NTn * 128 / 4);
    // output projection + skip blend (in-place xs, bf16 shadow xb)
    {
      GJob jp = {gb, Wp + (size_t)(18 + L * 2) * 16384, ab + (L * 2) * 128, xs, xb, xs, skipv + L * 2, NPn};
      GJob jat = {gb + (size_t)NPn * 128, Wp + (size_t)(19 + L * 2) * 16384, ab + (L * 2 + 1) * 128,
                  xs + (size_t)NPn * 128, xb + (size_t)NPn * 128, xs + (size_t)NPn * 128, skipv + L * 2 + 1, NAn};
      gemm_k<2><<<gg, 256, 0, stream>>>(jp, jat);
    }
  }
}

// Round 6
// 706.523 us; speedup vs baseline: 3.3515x; 1.3785x over previous
//
#include <hip/hip_runtime.h>
#include <math.h>

#define NPn 100000
#define NAn 50000
#define NTn 150000
#define En  200000
#define SCAN_N 250000

typedef short s16x8 __attribute__((ext_vector_type(8)));
typedef float f32x4 __attribute__((ext_vector_type(4)));

__device__ __forceinline__ unsigned short f2bfbits(float f) {
  unsigned u = __builtin_bit_cast(unsigned, f);
  return (unsigned short)((u + 0x7fffu + ((u >> 16) & 1u)) >> 16);
}
__device__ __forceinline__ float bf2f(unsigned short b) {
  return __builtin_bit_cast(float, (unsigned)b << 16);
}
__device__ __forceinline__ float gelu_f(float v) {
  return 0.5f * v * (1.f + erff(v * 0.70710678118654752f));
}

// ---------------- CSR build (combined over 3 edge types) ----------------
__global__ __launch_bounds__(256) void hist3_k(const int* __restrict__ e0, const int* __restrict__ e1,
                                               const int* __restrict__ e2, int* __restrict__ deg) {
  int i = blockIdx.x * 256 + threadIdx.x;
  int et = blockIdx.y;
  if (i >= En) return;
  const int* d = et == 0 ? e0 : (et == 1 ? e1 : e2);
  int etoff = et == 0 ? 0 : (et == 1 ? 100000 : 200000);
  atomicAdd(&deg[etoff + d[En + i]], 1);
}

__global__ __launch_bounds__(256) void scan1_k(const int* __restrict__ deg, int* __restrict__ bsum) {
  int t = threadIdx.x, lane = t & 63, wv = t >> 6;
  int base = blockIdx.x * 1024 + t * 4;
  int a0 = 0, a1 = 0, a2 = 0, a3 = 0;
  if (base + 3 < SCAN_N) {
    int4 v = *reinterpret_cast<const int4*>(deg + base);
    a0 = v.x; a1 = v.y; a2 = v.z; a3 = v.w;
  } else {
    if (base + 0 < SCAN_N) a0 = deg[base + 0];
    if (base + 1 < SCAN_N) a1 = deg[base + 1];
    if (base + 2 < SCAN_N) a2 = deg[base + 2];
    if (base + 3 < SCAN_N) a3 = deg[base + 3];
  }
  int s = a0 + a1 + a2 + a3;
  #pragma unroll
  for (int d = 1; d < 64; d <<= 1) s += __shfl_xor(s, d);
  __shared__ int wt[4];
  if (lane == 0) wt[wv] = s;
  __syncthreads();
  if (t == 0) bsum[blockIdx.x] = wt[0] + wt[1] + wt[2] + wt[3];
}

__global__ __launch_bounds__(256) void scan2_k(int* __restrict__ bsum, int nb) {
  int t = threadIdx.x, lane = t & 63, wv = t >> 6;
  int v = (t < nb) ? bsum[t] : 0;
  int x = v;
  #pragma unroll
  for (int d = 1; d < 64; d <<= 1) {
    int y = __shfl_up(x, d);
    if (lane >= d) x += y;
  }
  __shared__ int wt[4];
  if (lane == 63) wt[wv] = x;
  __syncthreads();
  int off = 0;
  for (int w = 0; w < wv; ++w) off += wt[w];
  if (t < nb) bsum[t] = x + off - v;  // exclusive
}

__global__ __launch_bounds__(256) void scan3_k(const int* __restrict__ deg, const int* __restrict__ bpre,
                                               int* __restrict__ S) {
  int t = threadIdx.x, lane = t & 63, wv = t >> 6;
  int base = blockIdx.x * 1024 + t * 4;
  int a[4] = {0, 0, 0, 0};
  if (base + 3 < SCAN_N) {
    int4 v = *reinterpret_cast<const int4*>(deg + base);
    a[0] = v.x; a[1] = v.y; a[2] = v.z; a[3] = v.w;
  } else {
    #pragma unroll
    for (int j = 0; j < 4; ++j) if (base + j < SCAN_N) a[j] = deg[base + j];
  }
  int s = a[0] + a[1] + a[2] + a[3];
  int x = s;
  #pragma unroll
  for (int d = 1; d < 64; d <<= 1) {
    int y = __shfl_up(x, d);
    if (lane >= d) x += y;
  }
  __shared__ int wt[4];
  if (lane == 63) wt[wv] = x;
  __syncthreads();
  int off = bpre[blockIdx.x];
  for (int w = 0; w < wv; ++w) off += wt[w];
  int ex = off + x - s;
  #pragma unroll
  for (int j = 0; j < 4; ++j) {
    int idx = base + j;
    if (idx < SCAN_N) {
      S[idx] = ex;
      ex += a[j];
      if (idx == SCAN_N - 1) S[SCAN_N] = ex;
    }
  }
}

__global__ __launch_bounds__(256) void fill3_k(const int* __restrict__ e0, const int* __restrict__ e1,
                                               const int* __restrict__ e2, int* cur, int* __restrict__ col) {
  int i = blockIdx.x * 256 + threadIdx.x;
  int et = blockIdx.y;
  if (i >= En) return;
  const int* ep = et == 0 ? e0 : (et == 1 ? e1 : e2);
  int etoff = et == 0 ? 0 : (et == 1 ? 100000 : 200000);
  int p = atomicAdd(&cur[etoff + ep[En + i]], 1);
  col[p] = ep[i];
}

// ---------------- fused relation weights (fp32) ----------------
__global__ __launch_bounds__(256) void fuse_k(const float* __restrict__ kW, const float* __restrict__ kb,
                                              const float* __restrict__ vW, const float* __restrict__ vb,
                                              const float* __restrict__ a_rel, const float* __restrict__ m_rel,
                                              float* __restrict__ Wf, float* __restrict__ bfv) {
  int b = blockIdx.x;
  int L = b / 6, et = (b % 6) / 2, which = b & 1;
  int s_t = (et == 1) ? 1 : 0;
  const float* W = which ? vW : kW;
  const float* bb = which ? vb : kb;
  const float* R = which ? m_rel : a_rel;
  const float* Wsrc = W + (size_t)(L * 2 + s_t) * 128 * 128;
  const float* bsrc = bb + (size_t)(L * 2 + s_t) * 128;
  const float* Rsrc = R + (size_t)(L * 3 + et) * 4 * 32 * 32;
  float* Wdst = Wf + (size_t)b * 128 * 128;
  float* bdst = bfv + (size_t)b * 128;
  for (int idx = threadIdx.x; idx < 128 * 128; idx += 256) {
    int i = idx >> 7, c = idx & 127;
    int h = c >> 5, cc = c & 31;
    const float* r = Rsrc + (size_t)h * 32 * 32 + cc;
    const float* w = Wsrc + (size_t)i * 128 + h * 32;
    float s = 0.f;
    #pragma unroll 8
    for (int d = 0; d < 32; ++d) s += w[d] * r[d * 32];
    Wdst[idx] = s;
  }
  for (int c = threadIdx.x; c < 128; c += 256) {
    int h = c >> 5, cc = c & 31;
    float s = 0.f;
    for (int d = 0; d < 32; ++d) s += bsrc[h * 32 + d] * Rsrc[((size_t)h * 32 + d) * 32 + cc];
    bdst[c] = s;
  }
}

// ---------------- pack weights to bf16 B-fragment order ----------------
// Wp[m][ks][ct][lane][i] = bf16(W[k][n]), k=ks*32+(lane>>4)*8+i, n=ct*16+(lane&15)
__global__ __launch_bounds__(256) void pack_k(const float* __restrict__ linW, const float* __restrict__ qW,
                                              const float* __restrict__ aW, const float* __restrict__ Wf,
                                              unsigned short* __restrict__ Wp) {
  int m = blockIdx.x;
  const float* src;
  if (m < 2) src = linW + (size_t)m * 16384;
  else if (m < 6) src = qW + (size_t)(m - 2) * 16384;
  else if (m < 18) src = Wf + (size_t)(m - 6) * 16384;
  else src = aW + (size_t)(m - 18) * 16384;
  int lane = threadIdx.x & 63, wv = threadIdx.x >> 6;
  unsigned short* dst = Wp + (size_t)m * 16384;
  for (int ct = 0; ct < 8; ++ct) {
    s16x8 t;
    #pragma unroll
    for (int i = 0; i < 8; ++i) {
      int k = wv * 32 + (lane >> 4) * 8 + i;
      int n = ct * 16 + (lane & 15);
      t[i] = (short)f2bfbits(src[k * 128 + n]);
    }
    *reinterpret_cast<s16x8*>(dst + ((size_t)(wv * 8 + ct) * 64 + lane) * 8) = t;
  }
}

// ---------------- input projection: fp32 X -> bf16 xb ----------------
struct IJob { const float* X; const unsigned short* W; const float* bias; unsigned short* Y; int N; };

__global__ __launch_bounds__(256, 2) void iproj_k(IJob ja, IJob jb) {
  IJob j = blockIdx.y ? jb : ja;
  int ntj = (j.N + 63) >> 6;
  int tile = blockIdx.x;
  if (tile >= ntj) return;
  int lane = threadIdx.x & 63, wv = threadIdx.x >> 6;
  int rowsLeft = j.N - tile * 64;

  __shared__ float xin[64 * 128];  // 32KB
  {
    const uint4* src = reinterpret_cast<const uint4*>(j.X + (size_t)tile * 64 * 128);
    uint4* dst = reinterpret_cast<uint4*>(xin);
    for (int c = threadIdx.x; c < 2048; c += 256) {
      int row = c >> 5;
      if (row < rowsLeft) dst[c] = src[c];
    }
  }
  __syncthreads();

  int lr = wv * 16 + (lane & 15);
  s16x8 af[4];
  #pragma unroll
  for (int ks = 0; ks < 4; ++ks) {
    const float* p = xin + lr * 128 + (lane >> 4) * 8 + ks * 32;
    s16x8 t;
    #pragma unroll
    for (int i = 0; i < 8; ++i) t[i] = (short)f2bfbits(p[i]);
    af[ks] = t;
  }

  s16x8 bfr[4][8];
  #pragma unroll
  for (int ks = 0; ks < 4; ++ks)
    #pragma unroll
    for (int ct = 0; ct < 8; ++ct)
      bfr[ks][ct] = *reinterpret_cast<const s16x8*>(j.W + ((size_t)(ks * 8 + ct) * 64 + lane) * 8);

  float bias_[8];
  #pragma unroll
  for (int ct = 0; ct < 8; ++ct) bias_[ct] = j.bias[ct * 16 + (lane & 15)];

  f32x4 acc[8];
  #pragma unroll
  for (int ct = 0; ct < 8; ++ct) acc[ct] = (f32x4){0.f, 0.f, 0.f, 0.f};
  #pragma unroll
  for (int ks = 0; ks < 4; ++ks)
    #pragma unroll
    for (int ct = 0; ct < 8; ++ct)
      acc[ct] = __builtin_amdgcn_mfma_f32_16x16x32_bf16(af[ks], bfr[ks][ct], acc[ct], 0, 0, 0);

  __syncthreads();  // all xin reads done before reuse as output staging
  unsigned short* ot = reinterpret_cast<unsigned short*>(xin);
  int c0 = lane & 15, r00 = wv * 16 + (lane >> 4) * 4;
  #pragma unroll
  for (int ct = 0; ct < 8; ++ct)
    #pragma unroll
    for (int i = 0; i < 4; ++i)
      ot[(r00 + i) * 128 + ct * 16 + c0] = f2bfbits(acc[ct][i] + bias_[ct]);
  __syncthreads();
  {
    const uint4* src = reinterpret_cast<const uint4*>(ot);
    uint4* dst = reinterpret_cast<uint4*>(j.Y + (size_t)tile * 64 * 128);
    for (int c = threadIdx.x; c < 1024; c += 256) {
      int row = c >> 4;
      if (row < rowsLeft) dst[c] = src[c];
    }
  }
}

// ---------------- fused Q/K/V projections (bf16 in, bf16 out) ----------------
struct QKVJob {
  const unsigned short* X; int N; int nm; int pad;
  const unsigned short* W[5];
  const float* bias[5];
  unsigned short* Y[5];
};

__global__ __launch_bounds__(256, 2) void qkv_k(QKVJob ja, QKVJob jb) {
  QKVJob j = blockIdx.y ? jb : ja;
  int ntj = (j.N + 63) >> 6;
  int tile = blockIdx.x;
  if (tile >= ntj) return;
  int lane = threadIdx.x & 63, wv = threadIdx.x >> 6;
  int rowsLeft = j.N - tile * 64;

  int arow = tile * 64 + wv * 16 + (lane & 15);
  if (arow >= j.N) arow = j.N - 1;
  const unsigned short* xp = j.X + (size_t)arow * 128 + (lane >> 4) * 8;
  s16x8 af[4];
  #pragma unroll
  for (int ks = 0; ks < 4; ++ks) af[ks] = *reinterpret_cast<const s16x8*>(xp + ks * 32);

  __shared__ unsigned short ot[64 * 128];  // 16KB
  int c0 = lane & 15, r00 = wv * 16 + (lane >> 4) * 4;

  for (int m = 0; m < j.nm; ++m) {
    s16x8 bfr[4][8];
    #pragma unroll
    for (int ks = 0; ks < 4; ++ks)
      #pragma unroll
      for (int ct = 0; ct < 8; ++ct)
        bfr[ks][ct] = *reinterpret_cast<const s16x8*>(j.W[m] + ((size_t)(ks * 8 + ct) * 64 + lane) * 8);
    float bias_[8];
    #pragma unroll
    for (int ct = 0; ct < 8; ++ct) bias_[ct] = j.bias[m][ct * 16 + (lane & 15)];

    f32x4 acc[8];
    #pragma unroll
    for (int ct = 0; ct < 8; ++ct) acc[ct] = (f32x4){0.f, 0.f, 0.f, 0.f};
    #pragma unroll
    for (int ks = 0; ks < 4; ++ks)
      #pragma unroll
      for (int ct = 0; ct < 8; ++ct)
        acc[ct] = __builtin_amdgcn_mfma_f32_16x16x32_bf16(af[ks], bfr[ks][ct], acc[ct], 0, 0, 0);

    if (m) __syncthreads();  // previous copy-out finished
    #pragma unroll
    for (int ct = 0; ct < 8; ++ct)
      #pragma unroll
      for (int i = 0; i < 4; ++i)
        ot[(r00 + i) * 128 + ct * 16 + c0] = f2bfbits(acc[ct][i] + bias_[ct]);
    __syncthreads();
    const uint4* src = reinterpret_cast<const uint4*>(ot);
    uint4* dst = reinterpret_cast<uint4*>(j.Y[m] + (size_t)tile * 64 * 128);
    for (int c = threadIdx.x; c < 1024; c += 256) {
      int row = c >> 4;
      if (row < rowsLeft) dst[c] = src[c];
    }
  }
}

// ---------------- output projection + skip blend ----------------
struct OJob {
  const unsigned short* G;    // gelu'd messages bf16 [N,128]
  const unsigned short* W;    // packed aW
  const float* bias;
  const unsigned short* skip; // bf16 x
  const float* skp;           // skip gate logit
  unsigned short* Yb;         // bf16 out (non-final)
  float* Yf;                  // fp32 out (final)
  int N;
};

template <int FINAL>
__global__ __launch_bounds__(256, 2) void oproj_k(OJob ja, OJob jb) {
  OJob j = blockIdx.y ? jb : ja;
  int ntj = (j.N + 63) >> 6;
  int tile = blockIdx.x;
  if (tile >= ntj) return;
  int lane = threadIdx.x & 63, wv = threadIdx.x >> 6;
  int rowsLeft = j.N - tile * 64;

  __shared__ unsigned short sk[64 * 128];           // 16KB skip stage (reused for bf16 out)
  __shared__ float of[FINAL ? 64 * 128 : 1];        // 32KB fp32 out stage (final only)
  {
    const uint4* src = reinterpret_cast<const uint4*>(j.skip + (size_t)tile * 64 * 128);
    uint4* dst = reinterpret_cast<uint4*>(sk);
    for (int c = threadIdx.x; c < 1024; c += 256) {
      int row = c >> 4;
      if (row < rowsLeft) dst[c] = src[c];
    }
  }

  int arow = tile * 64 + wv * 16 + (lane & 15);
  if (arow >= j.N) arow = j.N - 1;
  const unsigned short* xp = j.G + (size_t)arow * 128 + (lane >> 4) * 8;
  s16x8 af[4];
  #pragma unroll
  for (int ks = 0; ks < 4; ++ks) af[ks] = *reinterpret_cast<const s16x8*>(xp + ks * 32);

  s16x8 bfr[4][8];
  #pragma unroll
  for (int ks = 0; ks < 4; ++ks)
    #pragma unroll
    for (int ct = 0; ct < 8; ++ct)
      bfr[ks][ct] = *reinterpret_cast<const s16x8*>(j.W + ((size_t)(ks * 8 + ct) * 64 + lane) * 8);
  float bias_[8];
  #pragma unroll
  for (int ct = 0; ct < 8; ++ct) bias_[ct] = j.bias[ct * 16 + (lane & 15)];
  float g = 1.f / (1.f + __expf(-*j.skp));

  f32x4 acc[8];
  #pragma unroll
  for (int ct = 0; ct < 8; ++ct) acc[ct] = (f32x4){0.f, 0.f, 0.f, 0.f};
  #pragma unroll
  for (int ks = 0; ks < 4; ++ks)
    #pragma unroll
    for (int ct = 0; ct < 8; ++ct)
      acc[ct] = __builtin_amdgcn_mfma_f32_16x16x32_bf16(af[ks], bfr[ks][ct], acc[ct], 0, 0, 0);

  __syncthreads();  // skip stage complete
  int c0 = lane & 15, r00 = wv * 16 + (lane >> 4) * 4;
  #pragma unroll
  for (int ct = 0; ct < 8; ++ct)
    #pragma unroll
    for (int i = 0; i < 4; ++i) {
      int idx = (r00 + i) * 128 + ct * 16 + c0;
      float y = g * (acc[ct][i] + bias_[ct]) + (1.f - g) * bf2f(sk[idx]);
      if (FINAL) of[idx] = y;
      else sk[idx] = f2bfbits(y);  // own-element overwrite, safe
    }
  __syncthreads();
  if (FINAL) {
    const uint4* src = reinterpret_cast<const uint4*>(of);
    uint4* dst = reinterpret_cast<uint4*>(j.Yf + (size_t)tile * 64 * 128);
    for (int c = threadIdx.x; c < 2048; c += 256) {
      int row = c >> 5;
      if (row < rowsLeft) dst[c] = src[c];
    }
  } else {
    const uint4* src = reinterpret_cast<const uint4*>(sk);
    uint4* dst = reinterpret_cast<uint4*>(j.Yb + (size_t)tile * 64 * 128);
    for (int c = threadIdx.x; c < 1024; c += 256) {
      int row = c >> 4;
      if (row < rowsLeft) dst[c] = src[c];
    }
  }
}

// ---------------- edge attention: merged edge types per dst set, fused GELU ----------------
template <int NPARTS>
__global__ __launch_bounds__(256) void attn_k(const int* __restrict__ S, const int* __restrict__ col,
                                              const unsigned short* __restrict__ kt,
                                              const unsigned short* __restrict__ vt,
                                              const unsigned short* __restrict__ qb,
                                              unsigned short* __restrict__ gbuf,
                                              const float* __restrict__ prp0, const float* __restrict__ prp1,
                                              int n_dst, int qbase, int soff0, int soff1,
                                              int ktbase0, int ktbase1) {
  int node = (blockIdx.x * 256 + threadIdx.x) >> 6;
  if (node >= n_dst) return;
  int lane = threadIdx.x & 63;
  int h = lane >> 4;

  ushort2 qv = *reinterpret_cast<const ushort2*>(qb + (size_t)(qbase + node) * 128 + lane * 2);
  float q0 = bf2f(qv.x), q1 = bf2f(qv.y);

  float facc0 = 0.f, facc1 = 0.f;
  #pragma unroll
  for (int p = 0; p < NPARTS; ++p) {
    int soff = p ? soff1 : soff0;
    const unsigned short* ktb = kt + (size_t)(p ? ktbase1 : ktbase0) * 128;
    const unsigned short* vtb = vt + (size_t)(p ? ktbase1 : ktbase0) * 128;
    const float* prp = p ? prp1 : prp0;
    float pr = prp[h] * 0.17677669529663687f;  // p_rel * 1/sqrt(32)
    int rs = S[soff + node], re = S[soff + node + 1];
    if (rs < re) {
      float m = -3.0e38f, den = 0.f, n0 = 0.f, n1 = 0.f;
      for (int i = rs; i < re; ++i) {
        int s = col[i];
        ushort2 kv = *reinterpret_cast<const ushort2*>(ktb + (size_t)s * 128 + lane * 2);
        float pdot = q0 * bf2f(kv.x) + q1 * bf2f(kv.y);
        pdot += __shfl_xor(pdot, 1); pdot += __shfl_xor(pdot, 2);
        pdot += __shfl_xor(pdot, 4); pdot += __shfl_xor(pdot, 8);
        float pm = pdot * pr;
        ushort2 vv = *reinterpret_cast<const ushort2*>(vtb + (size_t)s * 128 + lane * 2);
        float nm = fmaxf(m, pm);
        float sc = __expf(m - nm);
        float w = __expf(pm - nm);
        den = den * sc + w;
        n0 = n0 * sc + w * bf2f(vv.x);
        n1 = n1 * sc + w * bf2f(vv.y);
        m = nm;
      }
      float inv = 1.f / den;
      facc0 += n0 * inv;
      facc1 += n1 * inv;
    }
  }
  ushort2 o;
  o.x = f2bfbits(gelu_f(facc0));
  o.y = f2bfbits(gelu_f(facc1));
  *reinterpret_cast<ushort2*>(gbuf + (size_t)(qbase + node) * 128 + lane * 2) = o;
}

// ---------------- host ----------------
extern "C" void kernel_launch(void* const* d_in, const int* in_sizes, int n_in,
                              void* d_out, int out_size, void* d_ws, size_t ws_size,
                              hipStream_t stream) {
  const float* x_paper  = (const float*)d_in[0];
  const float* x_author = (const float*)d_in[1];
  const int* e[3] = {(const int*)d_in[2], (const int*)d_in[3], (const int*)d_in[4]};
  const float* linW = (const float*)d_in[5];
  const float* linb = (const float*)d_in[6];
  const float* kW = (const float*)d_in[7];
  const float* kb = (const float*)d_in[8];
  const float* qW = (const float*)d_in[9];
  const float* qbv = (const float*)d_in[10];
  const float* vW = (const float*)d_in[11];
  const float* vb = (const float*)d_in[12];
  const float* aW = (const float*)d_in[13];
  const float* ab = (const float*)d_in[14];
  const float* skipv = (const float*)d_in[15];
  const float* a_rel = (const float*)d_in[16];
  const float* m_rel = (const float*)d_in[17];
  const float* prel  = (const float*)d_in[18];

  char* ws = (char*)d_ws;
  size_t off = 0;
  auto alloc = [&](size_t b) { char* p = ws + off; off = (off + b + 255) & ~(size_t)255; return p; };
  unsigned short* qbuf = (unsigned short*)alloc((size_t)NTn * 128 * 2);
  unsigned short* ktA  = (unsigned short*)alloc((size_t)SCAN_N * 128 * 2);  // rows: et0[0,100k) et1[100k,150k) et2[150k,250k)
  unsigned short* vtA  = (unsigned short*)alloc((size_t)SCAN_N * 128 * 2);
  unsigned short* gbuf = (unsigned short*)alloc((size_t)NTn * 128 * 2);
  unsigned short* xb   = (unsigned short*)alloc((size_t)NTn * 128 * 2);
  int* deg   = (int*)alloc((size_t)SCAN_N * 4);
  int* cur   = (int*)alloc((size_t)SCAN_N * 4);
  int* S     = (int*)alloc((size_t)(SCAN_N + 1) * 4);
  int* bsum  = (int*)alloc(256 * 4);
  int* col   = (int*)alloc((size_t)3 * En * 4);
  float* Wf  = (float*)alloc((size_t)12 * 16384 * 4);
  float* bfv = (float*)alloc((size_t)12 * 128 * 4);
  unsigned short* Wp = (unsigned short*)alloc((size_t)22 * 16384 * 2);

  // ---- CSR (combined) ----
  hipMemsetAsync(deg, 0, (size_t)SCAN_N * 4, stream);
  hist3_k<<<dim3(782, 3), 256, 0, stream>>>(e[0], e[1], e[2], deg);
  scan1_k<<<245, 256, 0, stream>>>(deg, bsum);
  scan2_k<<<1, 256, 0, stream>>>(bsum, 245);
  scan3_k<<<245, 256, 0, stream>>>(deg, bsum, S);
  hipMemcpyAsync(cur, S, (size_t)SCAN_N * 4, hipMemcpyDeviceToDevice, stream);
  fill3_k<<<dim3(782, 3), 256, 0, stream>>>(e[0], e[1], e[2], cur, col);

  // ---- weights ----
  fuse_k<<<12, 256, 0, stream>>>(kW, kb, vW, vb, a_rel, m_rel, Wf, bfv);
  pack_k<<<22, 256, 0, stream>>>(linW, qW, aW, Wf, Wp);

  const dim3 gg(1563, 2);

  // ---- input projection ----
  {
    IJob jp  = {x_paper,  Wp + 0 * 16384, linb,        xb,                       NPn};
    IJob jat = {x_author, Wp + 1 * 16384, linb + 128,  xb + (size_t)NPn * 128,   NAn};
    iproj_k<<<gg, 256, 0, stream>>>(jp, jat);
  }

  // kt/vt row bases per edge type
  const int ktbases[3] = {0, 100000, 150000};

  for (int L = 0; L < 2; ++L) {
    // fused Q/K/V
    {
      QKVJob jp{}, jat{};
      jp.X = xb; jp.N = NPn; jp.nm = 5;
      jp.W[0] = Wp + (size_t)(2 + L * 2) * 16384;      jp.bias[0] = qbv + (L * 2) * 128;            jp.Y[0] = qbuf;
      jp.W[1] = Wp + (size_t)(6 + L * 6 + 0) * 16384;  jp.bias[1] = bfv + (size_t)(L * 6 + 0) * 128; jp.Y[1] = ktA + (size_t)ktbases[0] * 128;
      jp.W[2] = Wp + (size_t)(6 + L * 6 + 1) * 16384;  jp.bias[2] = bfv + (size_t)(L * 6 + 1) * 128; jp.Y[2] = vtA + (size_t)ktbases[0] * 128;
      jp.W[3] = Wp + (size_t)(6 + L * 6 + 4) * 16384;  jp.bias[3] = bfv + (size_t)(L * 6 + 4) * 128; jp.Y[3] = ktA + (size_t)ktbases[2] * 128;
      jp.W[4] = Wp + (size_t)(6 + L * 6 + 5) * 16384;  jp.bias[4] = bfv + (size_t)(L * 6 + 5) * 128; jp.Y[4] = vtA + (size_t)ktbases[2] * 128;
      jat.X = xb + (size_t)NPn * 128; jat.N = NAn; jat.nm = 3;
      jat.W[0] = Wp + (size_t)(3 + L * 2) * 16384;     jat.bias[0] = qbv + (L * 2 + 1) * 128;        jat.Y[0] = qbuf + (size_t)NPn * 128;
      jat.W[1] = Wp + (size_t)(6 + L * 6 + 2) * 16384; jat.bias[1] = bfv + (size_t)(L * 6 + 2) * 128; jat.Y[1] = ktA + (size_t)ktbases[1] * 128;
      jat.W[2] = Wp + (size_t)(6 + L * 6 + 3) * 16384; jat.bias[2] = bfv + (size_t)(L * 6 + 3) * 128; jat.Y[2] = vtA + (size_t)ktbases[1] * 128;
      qkv_k<<<gg, 256, 0, stream>>>(jp, jat);
    }
    // merged edge attention + GELU
    attn_k<2><<<25000, 256, 0, stream>>>(S, col, ktA, vtA, qbuf, gbuf,
                                         prel + (size_t)(L * 3 + 0) * 4, prel + (size_t)(L * 3 + 1) * 4,
                                         NPn, 0, 0, 100000, ktbases[0], ktbases[1]);
    attn_k<1><<<12500, 256, 0, stream>>>(S, col, ktA, vtA, qbuf, gbuf,
                                         prel + (size_t)(L * 3 + 2) * 4, nullptr,
                                         NAn, NPn, 200000, 0, ktbases[2], 0);
    // output projection + skip blend
    {
      OJob jp  = {gbuf, Wp + (size_t)(18 + L * 2) * 16384, ab + (L * 2) * 128,
                  xb, skipv + L * 2, xb, (float*)d_out, NPn};
      OJob jat = {gbuf + (size_t)NPn * 128, Wp + (size_t)(19 + L * 2) * 16384, ab + (L * 2 + 1) * 128,
                  xb + (size_t)NPn * 128, skipv + L * 2 + 1, xb + (size_t)NPn * 128,
                  (float*)d_out + (size_t)NPn * 128, NAn};
      if (L == 0) oproj_k<0><<<gg, 256, 0, stream>>>(jp, jat);
      else        oproj_k<1><<<gg, 256, 0, stream>>>(jp, jat);
    }
  }
}